// Round 2
// baseline (774.781 us; speedup 1.0000x reference)
//
#include <hip/hip_runtime.h>
#include <hip/hip_bf16.h>

// Problem constants
#define HWN 9216              // 96*96
#define PLN (64 * HWN)        // one frame's feature plane (C=64)

__device__ __forceinline__ unsigned short f2bf(float v) {
    union { float f; unsigned u; } cv; cv.f = v;
    unsigned u = cv.u;
    u += 0x7fffu + ((u >> 16) & 1u);   // round-to-nearest-even
    return (unsigned short)(u >> 16);
}
__device__ __forceinline__ float bf2f(unsigned short b) {
    union { unsigned u; float f; } cv; cv.u = ((unsigned)b) << 16;
    return cv.f;
}

// Direct 3x3 conv over a 64-channel slab of the 128-channel concat input.
// centerPass=1: in = x[t=2], weight slab cin 64..127, out = wsC (no bias/addend).
// centerPass=0: in = x[t_f], weight slab cin 0..63, out = ofs[f], += wsC + b_off.
__global__ __launch_bounds__(256) void conv_off_kernel(
    const float* __restrict__ x,      // [5][64][9216]
    const float* __restrict__ w_off,  // [144][128][9]
    const float* __restrict__ b_off,  // [144] (neighbor pass only)
    const float* __restrict__ wsC,    // [144][9216] (neighbor pass only)
    float* __restrict__ outp,         // wsC (center) or ofs[4][144][9216]
    int centerPass)
{
    const int f = blockIdx.z;
    const int t = centerPass ? 2 : (f < 2 ? f : f + 1);
    const float* in = x + (size_t)t * PLN;
    const int cin_off = centerPass ? 64 : 0;
    const int oc0 = blockIdx.y * 4;
    const int p0 = blockIdx.x * 256;
    const int tid = threadIdx.x;

    __shared__ float wsm[4 * 64 * 9];   // [j][c][k]
    #pragma unroll
    for (int i = tid; i < 4 * 64 * 9; i += 256) {
        int j = i / 576; int ck = i % 576;
        wsm[i] = w_off[(size_t)(oc0 + j) * 1152 + (size_t)cin_off * 9 + ck];
    }
    __syncthreads();

    const int p = p0 + tid;
    const int y = p / 96, xx = p - y * 96;

    int off[9]; float msk[9];
    #pragma unroll
    for (int k = 0; k < 9; ++k) {
        int yy = y + k / 3 - 1;
        int xw = xx + k % 3 - 1;
        bool v = (yy >= 0) & (yy < 96) & (xw >= 0) & (xw < 96);
        int yc = min(max(yy, 0), 95);
        int xc = min(max(xw, 0), 95);
        off[k] = yc * 96 + xc;
        msk[k] = v ? 1.0f : 0.0f;
    }

    float acc0 = 0.f, acc1 = 0.f, acc2 = 0.f, acc3 = 0.f;
    #pragma unroll 4
    for (int c = 0; c < 64; ++c) {
        const float* base = in + (size_t)c * HWN;
        const float* wb = wsm + c * 9;
        #pragma unroll
        for (int k = 0; k < 9; ++k) {
            float v = base[off[k]] * msk[k];
            acc0 = fmaf(v, wb[k],        acc0);
            acc1 = fmaf(v, wb[576 + k],  acc1);
            acc2 = fmaf(v, wb[1152 + k], acc2);
            acc3 = fmaf(v, wb[1728 + k], acc3);
        }
    }

    float* op = centerPass ? outp : (outp + (size_t)f * 144 * HWN);
    if (!centerPass) {
        acc0 += wsC[(size_t)(oc0 + 0) * HWN + p] + b_off[oc0 + 0];
        acc1 += wsC[(size_t)(oc0 + 1) * HWN + p] + b_off[oc0 + 1];
        acc2 += wsC[(size_t)(oc0 + 2) * HWN + p] + b_off[oc0 + 2];
        acc3 += wsC[(size_t)(oc0 + 3) * HWN + p] + b_off[oc0 + 3];
    }
    op[(size_t)(oc0 + 0) * HWN + p] = acc0;
    op[(size_t)(oc0 + 1) * HWN + p] = acc1;
    op[(size_t)(oc0 + 2) * HWN + p] = acc2;
    op[(size_t)(oc0 + 3) * HWN + p] = acc3;
}

// Fused deformable sampling + (64 x 576) x (576 x 64px) GEMM per pixel tile.
__global__ __launch_bounds__(256) void deform_kernel(
    const float* __restrict__ x,      // [5][64][9216]
    const float* __restrict__ ofs,    // [4][144][9216]
    const float* __restrict__ w_dcn,  // [64][576]  (o, ci*9+k)
    const float* __restrict__ b_dcn,  // [64]
    float* __restrict__ out)          // [5][64][9216]
{
    const int f = blockIdx.y;
    const int t = f < 2 ? f : f + 1;
    const float* feat = x + (size_t)t * PLN;
    const float* offp = ofs + (size_t)f * 144 * HWN;
    const int p0 = blockIdx.x * 64;
    const int tid = threadIdx.x;

    __shared__ unsigned short smp[576 * 64];   // bf16 bits, [ci*9+k][pix]

    // ---- phase 1: sampling. 512 (g,pix) tasks, 2 per thread ----
    for (int task = tid; task < 512; task += 256) {
        const int g = task >> 6;
        const int pl = task & 63;
        const int p = p0 + pl;
        const int y = p / 96, xx = p - (p / 96) * 96;
        const float* ob = offp + (size_t)g * 18 * HWN + p;
        #pragma unroll
        for (int k = 0; k < 9; ++k) {
            float dy = ob[(size_t)(2 * k) * HWN];
            float dx = ob[(size_t)(2 * k + 1) * HWN];
            float ys = (float)(y + k / 3 - 1) + dy;
            float xs = (float)(xx + k % 3 - 1) + dx;
            float y0f = floorf(ys), x0f = floorf(xs);
            float wy = ys - y0f, wx = xs - x0f;
            int y0 = (int)y0f, x0 = (int)x0f;
            int y1 = y0 + 1, x1 = x0 + 1;
            bool vy0 = (y0 >= 0) & (y0 < 96);
            bool vy1 = (y1 >= 0) & (y1 < 96);
            bool vx0 = (x0 >= 0) & (x0 < 96);
            bool vx1 = (x1 >= 0) & (x1 < 96);
            int yc0 = min(max(y0, 0), 95), yc1 = min(max(y1, 0), 95);
            int xc0 = min(max(x0, 0), 95), xc1 = min(max(x1, 0), 95);
            int l00 = yc0 * 96 + xc0, l01 = yc0 * 96 + xc1;
            int l10 = yc1 * 96 + xc0, l11 = yc1 * 96 + xc1;
            float w00 = (1.f - wy) * (1.f - wx); if (!(vy0 & vx0)) w00 = 0.f;
            float w01 = (1.f - wy) * wx;         if (!(vy0 & vx1)) w01 = 0.f;
            float w10 = wy * (1.f - wx);         if (!(vy1 & vx0)) w10 = 0.f;
            float w11 = wy * wx;                 if (!(vy1 & vx1)) w11 = 0.f;
            #pragma unroll
            for (int cg = 0; cg < 8; ++cg) {
                const float* F = feat + (size_t)(g * 8 + cg) * HWN;
                float v = w00 * F[l00] + w01 * F[l01] + w10 * F[l10] + w11 * F[l11];
                smp[((g * 8 + cg) * 9 + k) * 64 + pl] = f2bf(v);
            }
        }
    }
    __syncthreads();

    // ---- phase 2: out[o][pix] = b[o] + sum_k W[o][k]*smp[k][pix] ----
    const int oq = tid >> 6;        // wave-uniform: 16 out-channels per wave
    const int pl = tid & 63;
    const float* wb = w_dcn + (size_t)(oq * 16) * 576;
    float acc[16];
    #pragma unroll
    for (int j = 0; j < 16; ++j) acc[j] = b_dcn[oq * 16 + j];

    for (int k = 0; k < 576; k += 4) {
        float s0 = bf2f(smp[(k + 0) * 64 + pl]);
        float s1 = bf2f(smp[(k + 1) * 64 + pl]);
        float s2 = bf2f(smp[(k + 2) * 64 + pl]);
        float s3 = bf2f(smp[(k + 3) * 64 + pl]);
        #pragma unroll
        for (int j = 0; j < 16; ++j) {
            const float4 w4 = *reinterpret_cast<const float4*>(wb + (size_t)j * 576 + k);
            acc[j] = fmaf(w4.x, s0, acc[j]);
            acc[j] = fmaf(w4.y, s1, acc[j]);
            acc[j] = fmaf(w4.z, s2, acc[j]);
            acc[j] = fmaf(w4.w, s3, acc[j]);
        }
    }

    float* op = out + (size_t)t * PLN + p0 + pl;
    #pragma unroll
    for (int j = 0; j < 16; ++j)
        op[(size_t)(oq * 16 + j) * HWN] = acc[j];
}

extern "C" void kernel_launch(void* const* d_in, const int* in_sizes, int n_in,
                              void* d_out, int out_size, void* d_ws, size_t ws_size,
                              hipStream_t stream) {
    const float* x     = (const float*)d_in[0];
    const float* w_off = (const float*)d_in[1];
    const float* b_off = (const float*)d_in[2];
    const float* w_dcn = (const float*)d_in[3];
    const float* b_dcn = (const float*)d_in[4];
    float* out = (float*)d_out;

    float* ofs = (float*)d_ws;                       // [4][144][9216]
    float* wsC = ofs + (size_t)4 * 144 * HWN;        // [144][9216]
    // ws usage: (4*144 + 144) * 9216 * 4 B = 26.5 MB

    // center frame passthrough
    hipMemcpyAsync(out + (size_t)2 * PLN, x + (size_t)2 * PLN,
                   (size_t)PLN * sizeof(float), hipMemcpyDeviceToDevice, stream);

    // center half of offset conv (frame-invariant, computed once)
    dim3 cgrid(36, 36, 1);
    conv_off_kernel<<<cgrid, 256, 0, stream>>>(x, w_off, nullptr, nullptr, wsC, 1);

    // neighbor half + combine + bias -> offsets for 4 frames
    dim3 ngrid(36, 36, 4);
    conv_off_kernel<<<ngrid, 256, 0, stream>>>(x, w_off, b_off, wsC, ofs, 0);

    // fused deformable sampling + projection
    dim3 dgrid(144, 4, 1);
    deform_kernel<<<dgrid, 256, 0, stream>>>(x, ofs, w_dcn, b_dcn, out);
}

// Round 5
// 385.553 us; speedup vs baseline: 2.0095x; 2.0095x over previous
//
#include <hip/hip_runtime.h>
#include <hip/hip_bf16.h>

#define HWN 9216              // 96*96
#define PLN (64 * HWN)        // one frame's feature plane (C=64)
#define SLD 584               // samp LDS row stride in bf16 elems (576 + 8 pad)

typedef __attribute__((ext_vector_type(8))) short bf16x8;
typedef __attribute__((ext_vector_type(4))) float f32x4;

__device__ __forceinline__ unsigned short f2bf(float v) {
    union { float f; unsigned u; } cv; cv.f = v;
    unsigned u = cv.u;
    u += 0x7fffu + ((u >> 16) & 1u);   // round-to-nearest-even
    return (unsigned short)(u >> 16);
}

// ---------------------------------------------------------------------------
// Reorder + bf16-cast w_dcn: wbf[o][g*72 + k*8 + cg] = w_dcn[o][(g*8+cg)*9 + k]
// ---------------------------------------------------------------------------
__global__ __launch_bounds__(256) void wprep_kernel(
    const float* __restrict__ w_dcn, unsigned short* __restrict__ wbf)
{
    int idx = blockIdx.x * 256 + threadIdx.x;
    if (idx >= 64 * 576) return;
    int o = idx / 576, c = idx % 576;
    int g = c / 72, rem = c % 72, k = rem >> 3, cg = rem & 7;
    wbf[idx] = f2bf(w_dcn[o * 576 + (g * 8 + cg) * 9 + k]);
}

// ---------------------------------------------------------------------------
// 3x3 conv over a 64-channel slab of the 128-ch concat input. 4 px/thread.
// centerPass=1: in = x[t=2], cin 64..127, out = wsC.
// centerPass=0: in = x[t_f], cin 0..63, out = ofs[f] (+= wsC + b_off).
// ---------------------------------------------------------------------------
__global__ __launch_bounds__(256) void conv_off_kernel(
    const float* __restrict__ x,      // [5][64][9216]
    const float* __restrict__ w_off,  // [144][128][9]
    const float* __restrict__ b_off,  // [144]
    const float* __restrict__ wsC,    // [144][9216]
    float* __restrict__ outp,
    int centerPass)
{
    const int f = blockIdx.z;
    const int t = centerPass ? 2 : (f < 2 ? f : f + 1);
    const float* in = x + (size_t)t * PLN;
    const int cin_off = centerPass ? 64 : 0;
    const int oc0 = blockIdx.y * 4;
    const int p0 = blockIdx.x * 1024;      // 1024 px/block, 4/thread
    const int tid = threadIdx.x;

    // weights in LDS as [c][j][12] (9 used + 3 pad) for float4 reads
    __shared__ float wsm[64 * 4 * 12];
    for (int i = tid; i < 64 * 4 * 9; i += 256) {
        int c = i / 36; int jk = i % 36; int j = jk / 9; int k = jk % 9;
        wsm[(c * 4 + j) * 12 + k] =
            w_off[(size_t)(oc0 + j) * 1152 + (size_t)(cin_off + c) * 9 + k];
    }
    __syncthreads();

    const int p = p0 + tid * 4;            // 96%4==0 -> 4 px share one row
    const int y = p / 96, x0 = p - y * 96;

    int row_off[3]; float mrow[3];
    #pragma unroll
    for (int r = 0; r < 3; ++r) {
        int yy = y + r - 1;
        mrow[r] = ((yy >= 0) & (yy < 96)) ? 1.f : 0.f;
        row_off[r] = min(max(yy, 0), 95) * 96;
    }
    const float mL = (x0 > 0) ? 1.f : 0.f;
    const float mR = (x0 < 92) ? 1.f : 0.f;
    const int xm = max(x0 - 1, 0);
    const int xp = min(x0 + 4, 95);
    float mLr[3], mRr[3];
    #pragma unroll
    for (int r = 0; r < 3; ++r) { mLr[r] = mrow[r] * mL; mRr[r] = mrow[r] * mR; }

    float a[4][4];                         // [oc][px]
    #pragma unroll
    for (int j = 0; j < 4; ++j)
        #pragma unroll
        for (int q = 0; q < 4; ++q) a[j][q] = 0.f;

    for (int c = 0; c < 64; ++c) {
        const float* base = in + (size_t)c * HWN;
        float w6[3][6];
        #pragma unroll
        for (int r = 0; r < 3; ++r) {
            const float* rp = base + row_off[r];
            float4 v4 = *reinterpret_cast<const float4*>(rp + x0);
            float le = rp[xm], re = rp[xp];
            w6[r][0] = le * mLr[r];
            w6[r][1] = v4.x * mrow[r];
            w6[r][2] = v4.y * mrow[r];
            w6[r][3] = v4.z * mrow[r];
            w6[r][4] = v4.w * mrow[r];
            w6[r][5] = re * mRr[r];
        }
        #pragma unroll
        for (int j = 0; j < 4; ++j) {
            const float* wp = &wsm[(c * 4 + j) * 12];
            float4 wa = *reinterpret_cast<const float4*>(wp);      // w00 w01 w02 w10
            float4 wb4 = *reinterpret_cast<const float4*>(wp + 4); // w11 w12 w20 w21
            float w8 = wp[8];                                      // w22
            #pragma unroll
            for (int q = 0; q < 4; ++q) {
                float s = a[j][q];
                s = fmaf(w6[0][q + 0], wa.x, s);
                s = fmaf(w6[0][q + 1], wa.y, s);
                s = fmaf(w6[0][q + 2], wa.z, s);
                s = fmaf(w6[1][q + 0], wa.w, s);
                s = fmaf(w6[1][q + 1], wb4.x, s);
                s = fmaf(w6[1][q + 2], wb4.y, s);
                s = fmaf(w6[2][q + 0], wb4.z, s);
                s = fmaf(w6[2][q + 1], wb4.w, s);
                s = fmaf(w6[2][q + 2], w8, s);
                a[j][q] = s;
            }
        }
    }

    float* op = centerPass ? outp : (outp + (size_t)f * 144 * HWN);
    #pragma unroll
    for (int j = 0; j < 4; ++j) {
        const int oc = oc0 + j;
        float4 r4 = { a[j][0], a[j][1], a[j][2], a[j][3] };
        if (!centerPass) {
            float4 cc = *reinterpret_cast<const float4*>(wsC + (size_t)oc * HWN + p);
            float bb = b_off[oc];
            r4.x += cc.x + bb; r4.y += cc.y + bb;
            r4.z += cc.z + bb; r4.w += cc.w + bb;
        }
        *reinterpret_cast<float4*>(op + (size_t)oc * HWN + p) = r4;
    }
}

// ---------------------------------------------------------------------------
// Fused deformable sampling + MFMA projection.
// Block: 512 thr (8 waves), 64-px tile. Phase 1: 1 (g,pl) task/thread.
// Phase 2: C[64 o][64 px] = Wbf[64x576] * samp[576x64] via 16x16x32 bf16 MFMA.
// ---------------------------------------------------------------------------
__global__ __launch_bounds__(512, 4) void deform_kernel(
    const float* __restrict__ x,            // [5][64][9216]
    const float* __restrict__ ofs,          // [4][144][9216]
    const unsigned short* __restrict__ wbf, // [64][576] bf16 (reordered)
    const float* __restrict__ b_dcn,        // [64]
    float* __restrict__ out)                // [5][64][9216]
{
    const int f = blockIdx.y;
    const int t = f < 2 ? f : f + 1;
    const float* feat = x + (size_t)t * PLN;
    const float* offp = ofs + (size_t)f * 144 * HWN;
    const int p0 = blockIdx.x * 64;
    const int tid = threadIdx.x;

    __shared__ unsigned short smp[64 * SLD];   // [pix][k'] bf16, k' = g*72+k*8+cg

    // ---- phase 1: sampling, one (g, pixel) task per thread ----
    {
        const int g = tid >> 6;
        const int pl = tid & 63;
        const int p = p0 + pl;
        const int y = p / 96, xx = p - y * 96;
        const float* ob = offp + (size_t)g * 18 * HWN + p;
        float dy[9], dx[9];
        #pragma unroll
        for (int k = 0; k < 9; ++k) {          // batch all 18 offset loads
            dy[k] = ob[(size_t)(2 * k) * HWN];
            dx[k] = ob[(size_t)(2 * k + 1) * HWN];
        }
        const float* fg = feat + (size_t)(g * 8) * HWN;
        unsigned short* srow = smp + pl * SLD + g * 72;
        #pragma unroll
        for (int k = 0; k < 9; ++k) {
            float ys = (float)(y + k / 3 - 1) + dy[k];
            float xs = (float)(xx + k % 3 - 1) + dx[k];
            float y0f = floorf(ys), x0f = floorf(xs);
            float wy = ys - y0f, wx = xs - x0f;
            int y0 = (int)y0f, x0 = (int)x0f;
            int y1 = y0 + 1, x1 = x0 + 1;
            bool vy0 = (y0 >= 0) & (y0 < 96);
            bool vy1 = (y1 >= 0) & (y1 < 96);
            bool vx0 = (x0 >= 0) & (x0 < 96);
            bool vx1 = (x1 >= 0) & (x1 < 96);
            int yc0 = min(max(y0, 0), 95), yc1 = min(max(y1, 0), 95);
            int xc0 = min(max(x0, 0), 95), xc1 = min(max(x1, 0), 95);
            int l00 = yc0 * 96 + xc0, l01 = yc0 * 96 + xc1;
            int l10 = yc1 * 96 + xc0, l11 = yc1 * 96 + xc1;
            float w00 = (1.f - wy) * (1.f - wx); if (!(vy0 & vx0)) w00 = 0.f;
            float w01 = (1.f - wy) * wx;         if (!(vy0 & vx1)) w01 = 0.f;
            float w10 = wy * (1.f - wx);         if (!(vy1 & vx0)) w10 = 0.f;
            float w11 = wy * wx;                 if (!(vy1 & vx1)) w11 = 0.f;
            bf16x8 pk;
            #pragma unroll
            for (int cg = 0; cg < 8; ++cg) {
                const float* F = fg + (size_t)cg * HWN;
                float v = w00 * F[l00] + w01 * F[l01] + w10 * F[l10] + w11 * F[l11];
                pk[cg] = (short)f2bf(v);
            }
            *reinterpret_cast<bf16x8*>(srow + k * 8) = pk;   // 16B aligned
        }
    }
    __syncthreads();

    // ---- phase 2: MFMA. wave w: o-tile (w&3), px-tiles (w>>2)*16 and +32 ----
    const int w = tid >> 6;
    const int l = tid & 63;
    const int o0 = (w & 3) * 16;
    const int pt0 = (w >> 2) * 16;
    const int lr = l & 15, lg = l >> 4;

    // preload all A fragments (register-resident: 18 x bf16x8 = 72 VGPR)
    bf16x8 afr[18];
    const unsigned short* wrow = wbf + (size_t)(o0 + lr) * 576 + lg * 8;
    #pragma unroll
    for (int s = 0; s < 18; ++s)
        afr[s] = *reinterpret_cast<const bf16x8*>(wrow + s * 32);

    f32x4 acc0 = {0.f, 0.f, 0.f, 0.f}, acc1 = {0.f, 0.f, 0.f, 0.f};
    const unsigned short* brow0 = smp + (pt0 + lr) * SLD + lg * 8;
    const unsigned short* brow1 = brow0 + 32 * SLD;
    #pragma unroll
    for (int s = 0; s < 18; ++s) {
        bf16x8 b0 = *reinterpret_cast<const bf16x8*>(brow0 + s * 32);
        bf16x8 b1 = *reinterpret_cast<const bf16x8*>(brow1 + s * 32);
        acc0 = __builtin_amdgcn_mfma_f32_16x16x32_bf16(afr[s], b0, acc0, 0, 0, 0);
        acc1 = __builtin_amdgcn_mfma_f32_16x16x32_bf16(afr[s], b1, acc1, 0, 0, 0);
    }

    float* op = out + (size_t)t * PLN + p0;
    #pragma unroll
    for (int r = 0; r < 4; ++r) {
        const int o = o0 + lg * 4 + r;              // C/D: row=(lane>>4)*4+r
        const float bb = b_dcn[o];
        op[(size_t)o * HWN + pt0 + lr] = acc0[r] + bb;        // col = lane&15
        op[(size_t)o * HWN + pt0 + 32 + lr] = acc1[r] + bb;
    }
}

extern "C" void kernel_launch(void* const* d_in, const int* in_sizes, int n_in,
                              void* d_out, int out_size, void* d_ws, size_t ws_size,
                              hipStream_t stream) {
    const float* x     = (const float*)d_in[0];
    const float* w_off = (const float*)d_in[1];
    const float* b_off = (const float*)d_in[2];
    const float* w_dcn = (const float*)d_in[3];
    const float* b_dcn = (const float*)d_in[4];
    float* out = (float*)d_out;

    float* ofs = (float*)d_ws;                               // [4][144][9216] f32
    float* wsC = ofs + (size_t)4 * 144 * HWN;                // [144][9216] f32
    unsigned short* wbf = (unsigned short*)(wsC + (size_t)144 * HWN); // [64][576] bf16
    // ws usage: 26.5 MB + 73.7 KB

    // bf16 weight reorder for the MFMA einsum
    wprep_kernel<<<144, 256, 0, stream>>>(w_dcn, wbf);

    // center frame passthrough
    hipMemcpyAsync(out + (size_t)2 * PLN, x + (size_t)2 * PLN,
                   (size_t)PLN * sizeof(float), hipMemcpyDeviceToDevice, stream);

    // center half of offset conv (frame-invariant, computed once)
    dim3 cgrid(9, 36, 1);
    conv_off_kernel<<<cgrid, 256, 0, stream>>>(x, w_off, nullptr, nullptr, wsC, 1);

    // neighbor half + combine + bias -> offsets for 4 frames
    dim3 ngrid(9, 36, 4);
    conv_off_kernel<<<ngrid, 256, 0, stream>>>(x, w_off, b_off, wsC, ofs, 0);

    // fused deformable sampling + MFMA projection
    dim3 dgrid(144, 4, 1);
    deform_kernel<<<dgrid, 512, 0, stream>>>(x, ofs, wbf, b_dcn, out);
}

// Round 6
// 145.216 us; speedup vs baseline: 5.3354x; 2.6550x over previous
//
#include <hip/hip_runtime.h>
#include <hip/hip_bf16.h>

#define HWN 9216              // 96*96
#define PLN (64 * HWN)        // one frame's feature plane (C=64)
#define SLD 584               // LDS K-row stride in bf16 elems (576 + 8 pad)

typedef __attribute__((ext_vector_type(8))) short bf16x8;
typedef __attribute__((ext_vector_type(4))) float f32x4;

__device__ __forceinline__ unsigned short f2bf(float v) {
    union { float f; unsigned u; } cv; cv.f = v;
    unsigned u = cv.u;
    u += 0x7fffu + ((u >> 16) & 1u);   // round-to-nearest-even
    return (unsigned short)(u >> 16);
}

// ---------------------------------------------------------------------------
// Reorder + bf16-cast w_dcn: wbf[o][g*72 + k*8 + cg] = w_dcn[o][(g*8+cg)*9 + k]
// ---------------------------------------------------------------------------
__global__ __launch_bounds__(256) void wprep_kernel(
    const float* __restrict__ w_dcn, unsigned short* __restrict__ wbf)
{
    int idx = blockIdx.x * 256 + threadIdx.x;
    if (idx >= 64 * 576) return;
    int o = idx / 576, c = idx % 576;
    int g = c / 72, rem = c % 72, k = rem >> 3, cg = rem & 7;
    wbf[idx] = f2bf(w_dcn[o * 576 + (g * 8 + cg) * 9 + k]);
}

// ---------------------------------------------------------------------------
// Reorder + bf16-cast w_off into two 64-cin slabs with K' = g*72 + k*8 + cg:
// wcbf[s][o][K'] = w_off[o][(s*64 + g*8+cg)*9 + k],  s=0 neighbor, s=1 center
// ---------------------------------------------------------------------------
__global__ __launch_bounds__(256) void wcprep_kernel(
    const float* __restrict__ w_off, unsigned short* __restrict__ wcbf)
{
    int idx = blockIdx.x * 256 + threadIdx.x;
    if (idx >= 2 * 144 * 576) return;
    int s = idx / (144 * 576);
    int o = (idx / 576) % 144;
    int kk = idx % 576;
    int g = kk / 72, rem = kk % 72, k = rem >> 3, cg = rem & 7;
    int cin = s * 64 + g * 8 + cg;
    wcbf[idx] = f2bf(w_off[(size_t)o * 1152 + (size_t)cin * 9 + k]);
}

// ---------------------------------------------------------------------------
// Offset conv as implicit-GEMM MFMA. 576 thr (9 waves), 64-px tile.
// Phase 1 (8 waves): im2col 64c x 9taps -> LDS [64 px][576 K] bf16 (masked
// shifted reads). Phase 2 (9 waves): wave w -> oc tile [16w..16w+16);
// C[144][64px] = Wslab[144x576] * im2col[576x64] via 16x16x32 bf16 MFMA.
// centerPass=1: x[t=2], slab cin 64..127, out = wsC.
// centerPass=0: x[t_f], slab cin 0..63, out = ofs[f] (+= wsC + b_off).
// ---------------------------------------------------------------------------
__global__ __launch_bounds__(576, 4) void conv_mfma_kernel(
    const float* __restrict__ x,            // [5][64][9216]
    const unsigned short* __restrict__ wcbf,// [2][144][576] bf16 (reordered)
    const float* __restrict__ b_off,        // [144]
    const float* __restrict__ wsC,          // [144][9216]
    float* __restrict__ outp,
    int centerPass)
{
    const int f = blockIdx.y;
    const int t = centerPass ? 2 : (f < 2 ? f : f + 1);
    const float* in = x + (size_t)t * PLN;
    const int p0 = blockIdx.x * 64;
    const int tid = threadIdx.x;

    __shared__ unsigned short smp[64 * SLD];   // [pix][K'] bf16

    // ---- phase 1: im2col, thread = (channel-group g, pixel pl) ----
    if (tid < 512) {
        const int g = tid >> 6, pl = tid & 63;
        const int p = p0 + pl;
        const int y = p / 96, xx = p - y * 96;
        const float* fg = in + (size_t)(g * 8) * HWN;
        unsigned short* srow = smp + pl * SLD + g * 72;
        int row_off[3]; float mrow[3];
        #pragma unroll
        for (int r = 0; r < 3; ++r) {
            int yy = y + r - 1;
            mrow[r] = ((yy >= 0) & (yy < 96)) ? 1.f : 0.f;
            row_off[r] = min(max(yy, 0), 95) * 96;
        }
        int xoff[3]; float mcol[3];
        #pragma unroll
        for (int d = 0; d < 3; ++d) {
            int xw = xx + d - 1;
            mcol[d] = ((xw >= 0) & (xw < 96)) ? 1.f : 0.f;
            xoff[d] = min(max(xw, 0), 95);
        }
        #pragma unroll
        for (int k = 0; k < 9; ++k) {
            const int r = k / 3, d = k % 3;
            const float m = mrow[r] * mcol[d];
            const int lin = row_off[r] + xoff[d];
            bf16x8 pk;
            #pragma unroll
            for (int cg = 0; cg < 8; ++cg)
                pk[cg] = (short)f2bf(fg[(size_t)cg * HWN + lin] * m);
            *reinterpret_cast<bf16x8*>(srow + k * 8) = pk;   // 16B aligned
        }
    }
    __syncthreads();

    // ---- phase 2: MFMA, wave w = oc tile, 4 px subtiles x 18 K-steps ----
    const int w = tid >> 6;          // 0..8
    const int l = tid & 63;
    const int lr = l & 15, lg = l >> 4;

    const unsigned short* wrow = wcbf
        + ((size_t)(centerPass ? 144 : 0) + w * 16 + lr) * 576 + lg * 8;
    bf16x8 afr[18];
    #pragma unroll
    for (int s = 0; s < 18; ++s)
        afr[s] = *reinterpret_cast<const bf16x8*>(wrow + s * 32);

    float* op = centerPass ? outp : (outp + (size_t)f * 144 * HWN);
    #pragma unroll
    for (int pt = 0; pt < 4; ++pt) {
        f32x4 acc = {0.f, 0.f, 0.f, 0.f};
        const unsigned short* brow = smp + (pt * 16 + lr) * SLD + lg * 8;
        #pragma unroll
        for (int s = 0; s < 18; ++s) {
            bf16x8 b = *reinterpret_cast<const bf16x8*>(brow + s * 32);
            acc = __builtin_amdgcn_mfma_f32_16x16x32_bf16(afr[s], b, acc, 0, 0, 0);
        }
        const int px = p0 + pt * 16 + lr;
        #pragma unroll
        for (int r = 0; r < 4; ++r) {
            const int o = w * 16 + lg * 4 + r;   // C/D: row=(lane>>4)*4+r, col=lane&15
            if (centerPass) {
                op[(size_t)o * HWN + px] = acc[r];
            } else {
                op[(size_t)o * HWN + px] =
                    acc[r] + wsC[(size_t)o * HWN + px] + b_off[o];
            }
        }
    }
}

// ---------------------------------------------------------------------------
// Fused deformable sampling + MFMA projection (unchanged from round 3).
// ---------------------------------------------------------------------------
__global__ __launch_bounds__(512, 4) void deform_kernel(
    const float* __restrict__ x,            // [5][64][9216]
    const float* __restrict__ ofs,          // [4][144][9216]
    const unsigned short* __restrict__ wbf, // [64][576] bf16 (reordered)
    const float* __restrict__ b_dcn,        // [64]
    float* __restrict__ out)                // [5][64][9216]
{
    const int f = blockIdx.y;
    const int t = f < 2 ? f : f + 1;
    const float* feat = x + (size_t)t * PLN;
    const float* offp = ofs + (size_t)f * 144 * HWN;
    const int p0 = blockIdx.x * 64;
    const int tid = threadIdx.x;

    __shared__ unsigned short smp[64 * SLD];   // [pix][k'] bf16, k' = g*72+k*8+cg

    // ---- phase 1: sampling, one (g, pixel) task per thread ----
    {
        const int g = tid >> 6;
        const int pl = tid & 63;
        const int p = p0 + pl;
        const int y = p / 96, xx = p - y * 96;
        const float* ob = offp + (size_t)g * 18 * HWN + p;
        float dy[9], dx[9];
        #pragma unroll
        for (int k = 0; k < 9; ++k) {          // batch all 18 offset loads
            dy[k] = ob[(size_t)(2 * k) * HWN];
            dx[k] = ob[(size_t)(2 * k + 1) * HWN];
        }
        const float* fg = feat + (size_t)(g * 8) * HWN;
        unsigned short* srow = smp + pl * SLD + g * 72;
        #pragma unroll
        for (int k = 0; k < 9; ++k) {
            float ys = (float)(y + k / 3 - 1) + dy[k];
            float xs = (float)(xx + k % 3 - 1) + dx[k];
            float y0f = floorf(ys), x0f = floorf(xs);
            float wy = ys - y0f, wx = xs - x0f;
            int y0 = (int)y0f, x0 = (int)x0f;
            int y1 = y0 + 1, x1 = x0 + 1;
            bool vy0 = (y0 >= 0) & (y0 < 96);
            bool vy1 = (y1 >= 0) & (y1 < 96);
            bool vx0 = (x0 >= 0) & (x0 < 96);
            bool vx1 = (x1 >= 0) & (x1 < 96);
            int yc0 = min(max(y0, 0), 95), yc1 = min(max(y1, 0), 95);
            int xc0 = min(max(x0, 0), 95), xc1 = min(max(x1, 0), 95);
            int l00 = yc0 * 96 + xc0, l01 = yc0 * 96 + xc1;
            int l10 = yc1 * 96 + xc0, l11 = yc1 * 96 + xc1;
            float w00 = (1.f - wy) * (1.f - wx); if (!(vy0 & vx0)) w00 = 0.f;
            float w01 = (1.f - wy) * wx;         if (!(vy0 & vx1)) w01 = 0.f;
            float w10 = wy * (1.f - wx);         if (!(vy1 & vx0)) w10 = 0.f;
            float w11 = wy * wx;                 if (!(vy1 & vx1)) w11 = 0.f;
            bf16x8 pk;
            #pragma unroll
            for (int cg = 0; cg < 8; ++cg) {
                const float* F = fg + (size_t)cg * HWN;
                float v = w00 * F[l00] + w01 * F[l01] + w10 * F[l10] + w11 * F[l11];
                pk[cg] = (short)f2bf(v);
            }
            *reinterpret_cast<bf16x8*>(srow + k * 8) = pk;   // 16B aligned
        }
    }
    __syncthreads();

    // ---- phase 2: MFMA. wave w: o-tile (w&3), px-tiles (w>>2)*16 and +32 ----
    const int w = tid >> 6;
    const int l = tid & 63;
    const int o0 = (w & 3) * 16;
    const int pt0 = (w >> 2) * 16;
    const int lr = l & 15, lg = l >> 4;

    // preload all A fragments (register-resident: 18 x bf16x8 = 72 VGPR)
    bf16x8 afr[18];
    const unsigned short* wrow = wbf + (size_t)(o0 + lr) * 576 + lg * 8;
    #pragma unroll
    for (int s = 0; s < 18; ++s)
        afr[s] = *reinterpret_cast<const bf16x8*>(wrow + s * 32);

    f32x4 acc0 = {0.f, 0.f, 0.f, 0.f}, acc1 = {0.f, 0.f, 0.f, 0.f};
    const unsigned short* brow0 = smp + (pt0 + lr) * SLD + lg * 8;
    const unsigned short* brow1 = brow0 + 32 * SLD;
    #pragma unroll
    for (int s = 0; s < 18; ++s) {
        bf16x8 b0 = *reinterpret_cast<const bf16x8*>(brow0 + s * 32);
        bf16x8 b1 = *reinterpret_cast<const bf16x8*>(brow1 + s * 32);
        acc0 = __builtin_amdgcn_mfma_f32_16x16x32_bf16(afr[s], b0, acc0, 0, 0, 0);
        acc1 = __builtin_amdgcn_mfma_f32_16x16x32_bf16(afr[s], b1, acc1, 0, 0, 0);
    }

    float* op = out + (size_t)t * PLN + p0;
    #pragma unroll
    for (int r = 0; r < 4; ++r) {
        const int o = o0 + lg * 4 + r;              // C/D: row=(lane>>4)*4+r
        const float bb = b_dcn[o];
        op[(size_t)o * HWN + pt0 + lr] = acc0[r] + bb;        // col = lane&15
        op[(size_t)o * HWN + pt0 + 32 + lr] = acc1[r] + bb;
    }
}

extern "C" void kernel_launch(void* const* d_in, const int* in_sizes, int n_in,
                              void* d_out, int out_size, void* d_ws, size_t ws_size,
                              hipStream_t stream) {
    const float* x     = (const float*)d_in[0];
    const float* w_off = (const float*)d_in[1];
    const float* b_off = (const float*)d_in[2];
    const float* w_dcn = (const float*)d_in[3];
    const float* b_dcn = (const float*)d_in[4];
    float* out = (float*)d_out;

    float* ofs = (float*)d_ws;                               // [4][144][9216] f32
    float* wsC = ofs + (size_t)4 * 144 * HWN;                // [144][9216] f32
    unsigned short* wbf  = (unsigned short*)(wsC + (size_t)144 * HWN); // [64][576]
    unsigned short* wcbf = wbf + (size_t)64 * 576;           // [2][144][576]
    // ws usage: 26.5 MB + 74 KB + 331 KB

    // weight reorders (bf16)
    wprep_kernel<<<144, 256, 0, stream>>>(w_dcn, wbf);
    wcprep_kernel<<<648, 256, 0, stream>>>(w_off, wcbf);

    // center frame passthrough
    hipMemcpyAsync(out + (size_t)2 * PLN, x + (size_t)2 * PLN,
                   (size_t)PLN * sizeof(float), hipMemcpyDeviceToDevice, stream);

    // center half of offset conv (frame-invariant, computed once)
    dim3 cgrid(144, 1);
    conv_mfma_kernel<<<cgrid, 576, 0, stream>>>(x, wcbf, b_off, nullptr, wsC, 1);

    // neighbor half + combine + bias -> offsets for 4 frames
    dim3 ngrid(144, 4);
    conv_mfma_kernel<<<ngrid, 576, 0, stream>>>(x, wcbf, b_off, wsC, ofs, 0);

    // fused deformable sampling + MFMA projection
    dim3 dgrid(144, 4, 1);
    deform_kernel<<<dgrid, 512, 0, stream>>>(x, ofs, wbf, b_dcn, out);
}